// Round 9
// baseline (478.840 us; speedup 1.0000x reference)
//
#include <hip/hip_runtime.h>

#define THREADS 320           // 5 waves/block; each wave owns one output row-pair

typedef float f4 __attribute__((ext_vector_type(4), aligned(4)));

// ---- named-scalar accumulators: NOTHING indexable, nothing can spill ----
#define DECL(OC) float A0_##OC = bias[OC], A1_##OC = bias[OC]

// load this ky's two input rows for channel IC straight from global (per-lane):
// row y+ky cols c..c+4 (dwordx4 + dword) and row y+ky+1 likewise. c<=59 so all
// accesses stay inside the channel row (col<=63); served by L1/L2.
#define LOADX(IC) do { \
    const float* pa_ = xg + (IC) * 4096; \
    f4 va_ = *(const f4*)pa_;         float a4_ = pa_[4]; \
    f4 vb_ = *(const f4*)(pa_ + 64);  float b4_ = pa_[68]; \
    xa0 = va_.x; xa1 = va_.y; xa2 = va_.z; xa3 = va_.w; xa4 = a4_; \
    xb0 = vb_.x; xb1 = vb_.y; xb2 = vb_.z; xb3 = vb_.w; xb4 = b4_; \
} while (0)

// one (oc,ic) 5-tap group at the loop's ky: 5 uniform weight loads (scalar
// pipe, lgkmcnt-only now), each weight feeds BOTH output rows
#define UPD2(OC, IC) do { \
    const float* wp_ = Wky + (OC) * 150 + (IC) * 25; \
    const float w0_ = wp_[0], w1_ = wp_[1], w2_ = wp_[2], w3_ = wp_[3], w4_ = wp_[4]; \
    A0_##OC = fmaf(xa0, w0_, A0_##OC);  A1_##OC = fmaf(xb0, w0_, A1_##OC); \
    A0_##OC = fmaf(xa1, w1_, A0_##OC);  A1_##OC = fmaf(xb1, w1_, A1_##OC); \
    A0_##OC = fmaf(xa2, w2_, A0_##OC);  A1_##OC = fmaf(xb2, w2_, A1_##OC); \
    A0_##OC = fmaf(xa3, w3_, A0_##OC);  A1_##OC = fmaf(xb3, w3_, A1_##OC); \
    A0_##OC = fmaf(xa4, w4_, A0_##OC);  A1_##OC = fmaf(xb4, w4_, A1_##OC); \
} while (0)

// Memory-permeable scheduling fence: VALU pinned (caps accumulator live
// ranges), SALU/SMEM + VMEM may cross (prefetch next chan under this FMA run)
#define SBAR __builtin_amdgcn_sched_barrier(0x4 | 0x10 | 0x20)

// per input channel: its 10 connected output maps
#define CHAN0 LOADX(0); UPD2(0,0);  UPD2(4,0);  UPD2(5,0);  UPD2(6,0);  UPD2(9,0);  UPD2(10,0); UPD2(11,0); UPD2(12,0); UPD2(14,0); UPD2(15,0); SBAR
#define CHAN1 LOADX(1); UPD2(0,1);  UPD2(1,1);  UPD2(5,1);  UPD2(6,1);  UPD2(7,1);  UPD2(10,1); UPD2(11,1); UPD2(12,1); UPD2(13,1); UPD2(15,1); SBAR
#define CHAN2 LOADX(2); UPD2(0,2);  UPD2(1,2);  UPD2(2,2);  UPD2(6,2);  UPD2(7,2);  UPD2(8,2);  UPD2(11,2); UPD2(13,2); UPD2(14,2); UPD2(15,2); SBAR
#define CHAN3 LOADX(3); UPD2(1,3);  UPD2(2,3);  UPD2(3,3);  UPD2(6,3);  UPD2(7,3);  UPD2(8,3);  UPD2(9,3);  UPD2(12,3); UPD2(14,3); UPD2(15,3); SBAR
#define CHAN4 LOADX(4); UPD2(2,4);  UPD2(3,4);  UPD2(4,4);  UPD2(7,4);  UPD2(8,4);  UPD2(9,4);  UPD2(10,4); UPD2(12,4); UPD2(13,4); UPD2(15,4); SBAR
#define CHAN5 LOADX(5); UPD2(3,5);  UPD2(4,5);  UPD2(5,5);  UPD2(8,5);  UPD2(9,5);  UPD2(10,5); UPD2(11,5); UPD2(13,5); UPD2(14,5); UPD2(15,5); SBAR

#define ST(T, OC) op[(OC) * 3600 + (T) * 60] = A##T##_##OC

__global__ __launch_bounds__(THREADS, 4)
void c3_conv(const float* __restrict__ x, const float* __restrict__ W,
             const float* __restrict__ bias, float* __restrict__ out) {
    const int blk  = blockIdx.x;
    const int img  = blk / 6;
    const int band = blk - img * 6;          // 0..5
    const int t    = threadIdx.x;
    const int w    = t >> 6;                 // wave 0..4
    const int lane = t & 63;

    const int pair = band * 5 + w;           // 0..29
    const int y    = 2 * pair;               // first output row (0..58)
    const int c    = lane < 59 ? lane : 59;  // clamped column: lanes 60-63 mirror 59

    // per-thread base: x[img][0][y][c]; channel stride 4096 floats, row stride 64
    const float* xbase = x + (size_t)img * 24576 + y * 64 + c;

    DECL(0);  DECL(1);  DECL(2);  DECL(3);  DECL(4);  DECL(5);  DECL(6);  DECL(7);
    DECL(8);  DECL(9);  DECL(10); DECL(11); DECL(12); DECL(13); DECL(14); DECL(15);

    float xa0, xa1, xa2, xa3, xa4;           // row y+ky, cols c..c+4
    float xb0, xb1, xb2, xb3, xb4;           // row y+ky+1

    // runtime ky loop bounds the scheduler window, keeps body ~5 KB (fits I$)
    #pragma unroll 1
    for (int ky = 0; ky < 5; ++ky) {
        const float* xg  = xbase + ky * 64;  // lane-divergent VMEM base
        const float* Wky = W + ky * 5;       // uniform SGPR base
        CHAN0; CHAN1; CHAN2; CHAN3; CHAN4; CHAN5;
    }

    if (lane < 60) {
        float* op = out + (size_t)img * 57600 + (size_t)y * 60 + lane;
        ST(0,0);  ST(0,1);  ST(0,2);  ST(0,3);  ST(0,4);  ST(0,5);  ST(0,6);  ST(0,7);
        ST(0,8);  ST(0,9);  ST(0,10); ST(0,11); ST(0,12); ST(0,13); ST(0,14); ST(0,15);
        ST(1,0);  ST(1,1);  ST(1,2);  ST(1,3);  ST(1,4);  ST(1,5);  ST(1,6);  ST(1,7);
        ST(1,8);  ST(1,9);  ST(1,10); ST(1,11); ST(1,12); ST(1,13); ST(1,14); ST(1,15);
    }
}

extern "C" void kernel_launch(void* const* d_in, const int* in_sizes, int n_in,
                              void* d_out, int out_size, void* d_ws, size_t ws_size,
                              hipStream_t stream) {
    const float* x  = (const float*)d_in[0];
    const float* W  = (const float*)d_in[1];
    const float* b  = (const float*)d_in[2];
    float* out      = (float*)d_out;

    const int nimg = in_sizes[0] / (6 * 64 * 64);   // 2048
    dim3 grid(nimg * 6), block(THREADS);
    hipLaunchKernelGGL(c3_conv, grid, block, 0, stream, x, W, b, out);
}